// Round 12
// baseline (58.145 us; speedup 1.0000x reference)
//
#include <hip/hip_runtime.h>
#include <stdint.h>

// pooled[b,o] = x[b,:] . Wp[o,:] + biasp[o] + 0.25*(y[b,n0]+y[b,n0+1]+y[b,n0+64]+y[b,n0+65])
//   o = p*32+q, n0 = 128p+2q; Wp = 2x2-pooled W rows. out = pooled / mean(pooled).
// 3 dispatches: prep (x->bf16 + pool W/bias) -> gemm (256x128 tile, 16 waves
// = 4/SIMD at 1 block/CU, dbuf LDS, ONE barrier + ONE counted vmcnt(4) per
// K-tile, setprio MFMA clusters, y interleaved lag-2 into acc) -> norm.

#define KDIM 1024
#define NP   1024
#define BM 256
#define BN 128
#define BK 64
#define NBLK 256

typedef __bf16 bf16x8 __attribute__((ext_vector_type(8)));
typedef float f32x4 __attribute__((ext_vector_type(4)));
typedef _Float16 f16x4 __attribute__((ext_vector_type(4)));

__device__ __forceinline__ unsigned f2bf(float f) {
  union { float f; unsigned u; } v; v.f = f;
  unsigned r = v.u + 0x7fffu + ((v.u >> 16) & 1u);  // RNE
  return r >> 16;
}

__device__ __forceinline__ void gload_lds16(const void* g, void* l) {
  __builtin_amdgcn_global_load_lds(
      (const __attribute__((address_space(1))) void*)g,
      (__attribute__((address_space(3))) void*)l, 16, 0, 0);
}

// ---- kernel 1 (merged prep): x fp32->bf16 (blocks 0..4095), pool W+bias ----
__global__ void k_prep(const float* __restrict__ x, const float* __restrict__ W,
                       const float* __restrict__ bias,
                       unsigned short* __restrict__ xb, unsigned short* __restrict__ wp,
                       float* __restrict__ biasp) {
  int b = blockIdx.x;
  int t = threadIdx.x;
  if (b < 4096) {
    int i = b * 256 + t;  // 8 elems per thread
    const float4* x4 = (const float4*)x;
    float4 a = x4[i * 2], c = x4[i * 2 + 1];
    uint4 o;
    o.x = f2bf(a.x) | (f2bf(a.y) << 16);
    o.y = f2bf(a.z) | (f2bf(a.w) << 16);
    o.z = f2bf(c.x) | (f2bf(c.y) << 16);
    o.w = f2bf(c.z) | (f2bf(c.w) << 16);
    ((uint4*)xb)[i] = o;
  } else {
    int o = b - 4096;  // pooled feature index
    int r0 = ((o >> 5) << 7) + ((o & 31) << 1);
    const float4* W4 = (const float4*)W;
    float4 w0 = W4[(r0) * 256 + t];
    float4 w1 = W4[(r0 + 1) * 256 + t];
    float4 w2 = W4[(r0 + 64) * 256 + t];
    float4 w3 = W4[(r0 + 65) * 256 + t];
    float ax = 0.25f * (w0.x + w1.x + w2.x + w3.x);
    float ay = 0.25f * (w0.y + w1.y + w2.y + w3.y);
    float az = 0.25f * (w0.z + w1.z + w2.z + w3.z);
    float aw = 0.25f * (w0.w + w1.w + w2.w + w3.w);
    uint2 pk;
    pk.x = f2bf(ax) | (f2bf(ay) << 16);
    pk.y = f2bf(az) | (f2bf(aw) << 16);
    ((uint2*)wp)[o * 256 + t] = pk;
    if (t == 0)
      biasp[o] = 0.25f * (bias[r0] + bias[r0 + 1] + bias[r0 + 64] + bias[r0 + 65]);
  }
}

// ---- kernel 2: GEMM 256x128, 16 waves, 1 barrier + 1 vmcnt per K-tile ----
__global__ __launch_bounds__(1024, 4) void k_gemm(
    const unsigned short* __restrict__ xb, const unsigned short* __restrict__ wp,
    const float* __restrict__ biasp, const float* __restrict__ y,
    float* __restrict__ out, _Float16* __restrict__ ph,
    float* __restrict__ partials, int use16) {
  // buf in {0,1}: A(buf)=smem+buf*49152 (32KB), B(buf)=+32768 (16KB)
  __shared__ char smem[98304];

  int bid = blockIdx.x;
  int wg = (bid & 7) * 32 + (bid >> 3);  // XCD swizzle, 256 = 8*32 bijective
  int bm0 = (wg >> 3) * BM;   // 32 row tiles
  int bn0 = (wg & 7) * BN;    // 8 col tiles

  int tid = threadIdx.x;
  int lane = tid & 63;
  int wid = tid >> 6;               // 0..15
  int wr = wid >> 1, wc = wid & 1;  // wave tile 32x64: rows wr*32 (0..7), cols wc*64

  f32x4 acc[2][4];
#pragma unroll
  for (int i = 0; i < 2; i++)
#pragma unroll
    for (int j = 0; j < 4; j++) acc[i][j] = (f32x4)0.0f;

  // staging: 1024 thr x 16B = 16KB/call -> 128 rows/call.
  // A 32KB = 2 calls, B 16KB = 1 call. LDS dest linear; SOURCE col chunk
  // pre-swizzled by (lane&7)^(lane>>3) (both-sides involution with read).
  int srow = tid >> 3;  // 0..127
  int scol = (((lane & 7) ^ (lane >> 3)) << 3);
  const unsigned short* aSrc = xb + (size_t)(bm0 + srow) * KDIM + scol;
  const unsigned short* bSrc = wp + (size_t)(bn0 + srow) * KDIM + scol;
  int ldsOff = wid * 1024;

  int rbase = (lane & 15) * 128;
  int xorv = (lane & 7) << 4;
  int cb0 = (((lane >> 4) * 16)) ^ xorv;
  int cb1 = ((64 + (lane >> 4) * 16)) ^ xorv;

  // y: 32 outputs/thread, q = mi*16+ni*4+j; tile t loads q=2t,2t+1 (4 dwordx2),
  // consumed lag-2 into acc (2-slot rotating window).
  const float2* y2 = (const float2*)y;
  int r_l = (lane >> 4) * 4;
  int c_l = lane & 15;
  int yrb = bm0 + wr * 32 + r_l;
  int yb[4];
#pragma unroll
  for (int ni = 0; ni < 4; ++ni) {
    int col = bn0 + wc * 64 + ni * 16 + c_l;
    yb[ni] = ((col >> 5) << 6) + (col & 31);
  }
  float2 yin[2][4];

#define STAGE_P1(buf, ks)                                                      \
  {                                                                            \
    int k0 = (ks) * BK;                                                        \
    char* ab = smem + (buf) * 49152 + ldsOff;                                  \
    gload_lds16(aSrc + k0, ab);                                                \
    gload_lds16(aSrc + (size_t)128 * KDIM + k0, ab + 16384);                   \
  }
#define STAGE_P2(buf, ks)                                                      \
  {                                                                            \
    int k0 = (ks) * BK;                                                        \
    char* bb = smem + (buf) * 49152 + 32768 + ldsOff;                          \
    gload_lds16(bSrc + k0, bb);                                                \
  }

#define YLD(slot, s, q)                                                        \
  {                                                                            \
    const float2* pp = y2 +                                                    \
        (size_t)(yrb + (((q) >> 4) * 16) + ((q) & 3)) * 2048 + yb[((q) >> 2) & 3]; \
    asm volatile("global_load_dwordx2 %0, %1, off"                             \
                 : "=v"(yin[slot][s]) : "v"(pp) : "memory");                   \
    asm volatile("global_load_dwordx2 %0, %1, off offset:256"                  \
                 : "=v"(yin[slot][(s) + 1]) : "v"(pp) : "memory");             \
  }
#define YLOAD(slot, t) { YLD(slot, 0, 2 * (t)) YLD(slot, 2, 2 * (t) + 1) }
#define YCONS(slot, p)                                                         \
  {                                                                            \
    acc[(2 * (p)) >> 4][((2 * (p)) >> 2) & 3][(2 * (p)) & 3] +=                \
        0.25f * ((yin[slot][0].x + yin[slot][0].y) +                           \
                 (yin[slot][1].x + yin[slot][1].y));                           \
    acc[(2 * (p) + 1) >> 4][((2 * (p) + 1) >> 2) & 3][(2 * (p) + 1) & 3] +=    \
        0.25f * ((yin[slot][2].x + yin[slot][2].y) +                           \
                 (yin[slot][3].x + yin[slot][3].y));                           \
  }

#define FRAGS(av, bv, cbv, Ab, Bb)                                             \
  {                                                                            \
    _Pragma("unroll")                                                          \
    for (int mi = 0; mi < 2; ++mi)                                             \
      av[mi] = *(const bf16x8*)((Ab) + (wr * 32 + mi * 16) * 128 + rbase + (cbv)); \
    _Pragma("unroll")                                                          \
    for (int ni = 0; ni < 4; ++ni)                                             \
      bv[ni] = *(const bf16x8*)((Bb) + (wc * 64 + ni * 16) * 128 + rbase + (cbv)); \
  }
#define MM8(av, bv)                                                            \
  {                                                                            \
    _Pragma("unroll")                                                          \
    for (int mi = 0; mi < 2; ++mi)                                             \
      _Pragma("unroll")                                                        \
      for (int ni = 0; ni < 4; ++ni)                                           \
        acc[mi][ni] = __builtin_amdgcn_mfma_f32_16x16x32_bf16(                 \
            av[mi], bv[ni], acc[mi][ni], 0, 0, 0);                             \
  }

  // Per K-tile: issue order [A2, B1, Y4] = 7 events. Open wait vmcnt(4)
  // allows only Y_{t-1} outstanding -> S_t and Y_{t-2} retired. Stage of
  // tile t+1 writes the buffer vacated at tile t-1 (safe after t's barrier).
#define TILE(t, WSTR)                                                          \
  {                                                                            \
    asm volatile(WSTR ::: "memory");                                           \
    __builtin_amdgcn_sched_barrier(0);                                         \
    __builtin_amdgcn_s_barrier();                                              \
    if ((t) >= 2) YCONS(((t) - 2) & 1, (t) - 2);                               \
    const char* Ab = smem + ((t) & 1) * 49152;                                 \
    const char* Bb = Ab + 32768;                                               \
    bf16x8 a0[2], b0[4];                                                       \
    FRAGS(a0, b0, cb0, Ab, Bb);                                                \
    if ((t) < 15) STAGE_P1(((t) + 1) & 1, (t) + 1);                            \
    asm volatile("s_waitcnt lgkmcnt(0)" ::: "memory");                         \
    __builtin_amdgcn_sched_barrier(0);                                         \
    __builtin_amdgcn_s_setprio(1);                                             \
    MM8(a0, b0);                                                               \
    __builtin_amdgcn_s_setprio(0);                                             \
    bf16x8 a1[2], b1[4];                                                       \
    FRAGS(a1, b1, cb1, Ab, Bb);                                                \
    if ((t) < 15) STAGE_P2(((t) + 1) & 1, (t) + 1);                            \
    YLOAD((t) & 1, t);                                                         \
    asm volatile("s_waitcnt lgkmcnt(0)" ::: "memory");                         \
    __builtin_amdgcn_sched_barrier(0);                                         \
    __builtin_amdgcn_s_setprio(1);                                             \
    MM8(a1, b1);                                                               \
    __builtin_amdgcn_s_setprio(0);                                             \
  }

  // prologue: stage tile 0 fully
  STAGE_P1(0, 0);
  STAGE_P2(0, 0);

  TILE(0,  "s_waitcnt vmcnt(0)")
  TILE(1,  "s_waitcnt vmcnt(4)")
  TILE(2,  "s_waitcnt vmcnt(4)")
  TILE(3,  "s_waitcnt vmcnt(4)")
  TILE(4,  "s_waitcnt vmcnt(4)")
  TILE(5,  "s_waitcnt vmcnt(4)")
  TILE(6,  "s_waitcnt vmcnt(4)")
  TILE(7,  "s_waitcnt vmcnt(4)")
  TILE(8,  "s_waitcnt vmcnt(4)")
  TILE(9,  "s_waitcnt vmcnt(4)")
  TILE(10, "s_waitcnt vmcnt(4)")
  TILE(11, "s_waitcnt vmcnt(4)")
  TILE(12, "s_waitcnt vmcnt(4)")
  TILE(13, "s_waitcnt vmcnt(4)")
  TILE(14, "s_waitcnt vmcnt(4)")
  TILE(15, "s_waitcnt vmcnt(4)")

  asm volatile("s_waitcnt vmcnt(0)" ::: "memory");
  __builtin_amdgcn_sched_barrier(0);
  YCONS(0, 14);
  YCONS(1, 15);

  // epilogue: acc holds gemm + pooled y; add bias, store, block sum
  float tsum = 0.f;
  float bpv[4];
#pragma unroll
  for (int ni = 0; ni < 4; ++ni) bpv[ni] = biasp[bn0 + wc * 64 + ni * 16 + c_l];
#pragma unroll
  for (int mi = 0; mi < 2; ++mi) {
#pragma unroll
    for (int ni = 0; ni < 4; ++ni) {
      int col = bn0 + wc * 64 + ni * 16 + c_l;
#pragma unroll
      for (int j = 0; j < 4; ++j) {
        int row = bm0 + wr * 32 + mi * 16 + r_l + j;
        float val = acc[mi][ni][j] + bpv[ni];
        size_t o = (size_t)row * NP + col;
        if (use16) ph[o] = (_Float16)val;
        else out[o] = val;
        tsum += val;
      }
    }
  }
#pragma unroll
  for (int off = 32; off > 0; off >>= 1) tsum += __shfl_down(tsum, off);
  float* sm = (float*)smem;
  __syncthreads();
  if (lane == 0) sm[wid] = tsum;
  __syncthreads();
  if (tid == 0) {
    float s0 = ((sm[0] + sm[1]) + (sm[2] + sm[3])) +
               ((sm[4] + sm[5]) + (sm[6] + sm[7]));
    float s1 = ((sm[8] + sm[9]) + (sm[10] + sm[11])) +
               ((sm[12] + sm[13]) + (sm[14] + sm[15]));
    partials[bid] = s0 + s1;
  }
}

// ---- kernel 3: redundant per-block reduce of 256 partials; scale to f32 out ----
__global__ void k_norm(float* __restrict__ out, const _Float16* __restrict__ ph,
                       const float* __restrict__ partials, int use16) {
  __shared__ float s[256];
  int t = threadIdx.x;
  s[t] = partials[t];
  __syncthreads();
#pragma unroll
  for (int off = 128; off > 0; off >>= 1) {
    if (t < off) s[t] += s[t + off];
    __syncthreads();
  }
  float inv = 8388608.0f / s[0];  // (B*NP)/total
  int i = blockIdx.x * 256 + t;   // float4 index
  float4* o4 = (float4*)out;
  if (use16) {
    f16x4 hv = ((const f16x4*)ph)[i];
    float4 v;
    v.x = (float)hv[0] * inv;
    v.y = (float)hv[1] * inv;
    v.z = (float)hv[2] * inv;
    v.w = (float)hv[3] * inv;
    o4[i] = v;
  } else {
    float4 v = o4[i];
    v.x *= inv; v.y *= inv; v.z *= inv; v.w *= inv;
    o4[i] = v;
  }
}

extern "C" void kernel_launch(void* const* d_in, const int* in_sizes, int n_in,
                              void* d_out, int out_size, void* d_ws, size_t ws_size,
                              hipStream_t stream) {
  (void)in_sizes; (void)n_in; (void)out_size;
  const float* x = (const float*)d_in[0];
  const float* y = (const float*)d_in[1];
  const float* W = (const float*)d_in[2];
  const float* bias = (const float*)d_in[3];
  float* out = (float*)d_out;

  char* ws = (char*)d_ws;
  unsigned short* xb = (unsigned short*)(ws);                 // 16 MiB
  unsigned short* wp = (unsigned short*)(ws + 16777216);      // 2 MiB
  float* biasp = (float*)(ws + 16777216 + 2097152);           // 4 KiB
  float* partials = (float*)(ws + 16777216 + 2097152 + 4096); // 1 KiB
  _Float16* ph = (_Float16*)(ws + 20971520);                  // 16 MiB
  int use16 = (ws_size >= (size_t)20971520 + 16777216) ? 1 : 0;

  hipLaunchKernelGGL(k_prep, dim3(5120), dim3(256), 0, stream, x, W, bias, xb, wp, biasp);
  hipLaunchKernelGGL(k_gemm, dim3(NBLK), dim3(1024), 0, stream, xb, wp, biasp, y, out, ph, partials, use16);
  hipLaunchKernelGGL(k_norm, dim3(8192), dim3(256), 0, stream, out, ph, partials, use16);
}